// Round 2
// baseline (396.202 us; speedup 1.0000x reference)
//
#include <hip/hip_runtime.h>
#include <cstdint>
#include <cstddef>

typedef unsigned short u16;
typedef unsigned int   u32;
typedef __attribute__((ext_vector_type(4))) float  f32x4;
typedef __attribute__((ext_vector_type(8))) __bf16 bf16x8;

#define PSW  1056   // staged padded-image row width (need 1050, keep 16B-friendly)
#define ASTR 72     // LDS row stride (elems) for As/Bs: 64 + 8 pad (4-bank rotation)

static __device__ __forceinline__ float b2f(u32 u) {
  union { u32 i; float f; } c; c.i = u << 16; return c.f;
}
static __device__ __forceinline__ u16 f2b(float f) {
  union { float f; u32 i; } c; c.f = f;
  return (u16)((c.i + 0x7FFFu + ((c.i >> 16) & 1u)) >> 16);  // RNE
}

// ---- kernel 0: transpose+cast lin_w (fp32, K=1024 x N=512) -> Bt (bf16, N=512 x K=1024)
__global__ __launch_bounds__(256) void transpose_w(const float* __restrict__ lw,
                                                   u16* __restrict__ bt) {
  __shared__ u16 tile[64][65];
  const int t  = threadIdx.x;
  const int c  = t & 63, r0 = t >> 6;
  const int n0 = blockIdx.x * 64;   // over N=512 -> grid.x = 8
  const int k0 = blockIdx.y * 64;   // over K=1024 -> grid.y = 16
#pragma unroll
  for (int rr = 0; rr < 16; ++rr) {
    const int r = r0 * 16 + rr;
    tile[r][c] = f2b(lw[(size_t)(k0 + r) * 512 + n0 + c]);
  }
  __syncthreads();
#pragma unroll
  for (int rr = 0; rr < 16; ++rr) {
    const int r = r0 * 16 + rr;
    bt[(size_t)(n0 + r) * 1024 + k0 + c] = tile[c][r];
  }
}

// ---- fused: slice + 3x3 conv + relu  ->  bf16 MFMA GEMM (M=32768,K=1024,N=512)
__global__ __launch_bounds__(256) void fused_kernel(
    const float* __restrict__ img,  // (64,1,32,4096) fp32
    const float* __restrict__ cw,   // (1,1,3,3) fp32
    const float* __restrict__ cb,   // (1,) fp32
    const u16* __restrict__ bt,     // (512,1024) bf16 = lin_w^T (from kernel 0)
    const float* __restrict__ lb,   // (512,) fp32
    float* __restrict__ out)        // (64,512,512) fp32
{
  __shared__ __align__(16) u16 Ps[4 * PSW];      //  8.4 KB: image rows h0-1..h0+2 (bf16)
  __shared__ __align__(16) u16 As[128 * ASTR];   // 18.4 KB: conv-out tile 128x64 (bf16)
  __shared__ __align__(16) u16 Bs[128 * ASTR];   // 18.4 KB: lin_w^T tile 128x64 (bf16)

  const int t  = threadIdx.x;
  const int nt = blockIdx.x;        // 0..3
  const int mt = blockIdx.y;        // 0..255
  const int b  = mt >> 2;
  const int s0 = (mt & 3) << 7;     // first slice of this M-tile
  const int X0 = s0 << 3;           // first padded-image column used
  const int n0 = nt << 7;

  const float* imgb = img + (size_t)b * 32 * 4096;

  float cwf[9];
#pragma unroll
  for (int i = 0; i < 9; ++i) cwf[i] = cw[i];
  const float bias = cb[0];

  const int wv = t >> 6, l = t & 63;
  const int wr = wv >> 1, wc = wv & 1;     // 2x2 wave grid over 128x128
  const int lq = l >> 4,  lr = l & 15;

  const int sl = t >> 1, hsel = t & 1;     // conv work: slice sl, row h0+hsel

  f32x4 acc[4][4];
#pragma unroll
  for (int i = 0; i < 4; ++i)
#pragma unroll
    for (int j = 0; j < 4; ++j) acc[i][j] = (f32x4)0.0f;

  for (int kk = 0; kk < 16; ++kk) {
    const int h0 = kk << 1;
    __syncthreads();   // previous iteration's frag reads done before restage

    // prefetch B tile (global, coalesced) into regs; LDS write happens later
    uint4 bsv[4];
#pragma unroll
    for (int p = 0; p < 4; ++p) {
      const int idx8 = t + (p << 8);
      const int n = idx8 >> 3, k8 = idx8 & 7;
      bsv[p] = *(const uint4*)(bt + (size_t)(n0 + n) * 1024 + (kk << 6) + (k8 << 3));
    }

    // stage Ps (bf16): padded-image rows h0-1..h0+2, columns X0-1 .. X0+1054
    // pad semantics: h outside [0,32) -> 0; x outside [0,4120) -> 0 (phantom,
    // never used by a live term); x in [0,12) or [4108,4120) -> 1.0
    for (int idx = t; idx < 4 * PSW; idx += 256) {
      const int r  = idx / PSW;
      const int xi = idx - r * PSW;
      const int h  = h0 - 1 + r;
      const int x  = X0 - 1 + xi;
      u16 v = 0;
      if (h >= 0 && h < 32 && x >= 0 && x < 4120)
        v = (x < 12 || x >= 4108) ? (u16)0x3F80 : f2b(imgb[h * 4096 + (x - 12)]);
      Ps[idx] = v;
    }
    __syncthreads();

    // conv -> As. This thread: slice sl, output row h = h0+hsel, 2 passes of 16 w.
    {
      const int pbase = (sl << 3);
#pragma unroll
      for (int wb = 0; wb < 32; wb += 16) {
        float o[16];
#pragma unroll
        for (int j = 0; j < 16; ++j) o[j] = bias;
#pragma unroll
        for (int dr = 0; dr < 3; ++dr) {
          // window covers slice-local cols wb-1 .. wb+16 (18 vals), 16B-aligned
          const u16* p = Ps + (hsel + dr) * PSW + pbase + wb;
          const uint4 va = *(const uint4*)p;
          const uint4 vb = *(const uint4*)(p + 8);
          const u32   vc = *(const u32*)(p + 16);
          float win[18];
          win[0]  = b2f(va.x & 0xffffu); win[1]  = b2f(va.x >> 16);
          win[2]  = b2f(va.y & 0xffffu); win[3]  = b2f(va.y >> 16);
          win[4]  = b2f(va.z & 0xffffu); win[5]  = b2f(va.z >> 16);
          win[6]  = b2f(va.w & 0xffffu); win[7]  = b2f(va.w >> 16);
          win[8]  = b2f(vb.x & 0xffffu); win[9]  = b2f(vb.x >> 16);
          win[10] = b2f(vb.y & 0xffffu); win[11] = b2f(vb.y >> 16);
          win[12] = b2f(vb.z & 0xffffu); win[13] = b2f(vb.z >> 16);
          win[14] = b2f(vb.w & 0xffffu); win[15] = b2f(vb.w >> 16);
          win[16] = b2f(vc & 0xffffu);   win[17] = b2f(vc >> 16);
          if (wb == 0) win[0]  = 0.f;    // slice-local col -1 (slice conv zero-pad)
          else         win[17] = 0.f;    // slice-local col 32
          const float w0 = cwf[dr * 3 + 0], w1 = cwf[dr * 3 + 1], w2 = cwf[dr * 3 + 2];
#pragma unroll
          for (int j = 0; j < 16; ++j)
            o[j] += w0 * win[j] + w1 * win[j + 1] + w2 * win[j + 2];
        }
        u32 pk[8];
#pragma unroll
        for (int q = 0; q < 8; ++q) {
          const u32 lo = f2b(fmaxf(o[2 * q],     0.f));
          const u32 hi = f2b(fmaxf(o[2 * q + 1], 0.f));
          pk[q] = lo | (hi << 16);
        }
        uint4* dst = (uint4*)(As + sl * ASTR + (hsel << 5) + wb);
        dst[0] = make_uint4(pk[0], pk[1], pk[2], pk[3]);
        dst[1] = make_uint4(pk[4], pk[5], pk[6], pk[7]);
      }
    }

    // write prefetched B tile to LDS ([n][k] so fragments are k-contiguous)
#pragma unroll
    for (int p = 0; p < 4; ++p) {
      const int idx8 = t + (p << 8);
      const int n = idx8 >> 3, k8 = idx8 & 7;
      *(uint4*)(Bs + n * ASTR + (k8 << 3)) = bsv[p];
    }
    __syncthreads();

    // MFMA: BK=64 as 2 chunks of K=32
#pragma unroll
    for (int kc = 0; kc < 2; ++kc) {
      const int ko = (kc << 5) + (lq << 3);
      bf16x8 af[4], bfv[4];
#pragma unroll
      for (int im = 0; im < 4; ++im)
        af[im] = __builtin_bit_cast(bf16x8,
            *(const uint4*)(As + (wr * 64 + im * 16 + lr) * ASTR + ko));
#pragma unroll
      for (int jn = 0; jn < 4; ++jn)
        bfv[jn] = __builtin_bit_cast(bf16x8,
            *(const uint4*)(Bs + (wc * 64 + jn * 16 + lr) * ASTR + ko));
#pragma unroll
      for (int im = 0; im < 4; ++im)
#pragma unroll
        for (int jn = 0; jn < 4; ++jn)
          acc[im][jn] = __builtin_amdgcn_mfma_f32_16x16x32_bf16(
              af[im], bfv[jn], acc[im][jn], 0, 0, 0);
    }
  }

  // epilogue: + lin_b, fp32 store. C/D layout: col=lane&15, row=quad*4+reg.
#pragma unroll
  for (int jn = 0; jn < 4; ++jn) {
    const int col = n0 + wc * 64 + jn * 16 + lr;
    const float lbv = lb[col];
#pragma unroll
    for (int im = 0; im < 4; ++im) {
      const int row0 = (mt << 7) + wr * 64 + im * 16 + (lq << 2);
#pragma unroll
      for (int r = 0; r < 4; ++r)
        out[(size_t)(row0 + r) * 512 + col] = acc[im][jn][r] + lbv;
    }
  }
}

extern "C" void kernel_launch(void* const* d_in, const int* in_sizes, int n_in,
                              void* d_out, int out_size, void* d_ws, size_t ws_size,
                              hipStream_t stream) {
  const float* img = (const float*)d_in[0];  // images  (64,1,32,4096) fp32
  const float* cw  = (const float*)d_in[1];  // conv_w  (1,1,3,3) fp32
  const float* cb  = (const float*)d_in[2];  // conv_b  (1,) fp32
  const float* lw  = (const float*)d_in[3];  // lin_w   (1024,512) fp32
  const float* lb  = (const float*)d_in[4];  // lin_b   (512,) fp32
  float* out = (float*)d_out;                // (64,512,512) fp32
  u16* btw = (u16*)d_ws;                     // 1 MB: lin_w^T as bf16

  transpose_w<<<dim3(8, 16), 256, 0, stream>>>(lw, btw);
  fused_kernel<<<dim3(4, 256), 256, 0, stream>>>(img, cw, cb, btw, lb, out);
}

// Round 3
// 246.203 us; speedup vs baseline: 1.6092x; 1.6092x over previous
//
#include <hip/hip_runtime.h>
#include <cstdint>
#include <cstddef>

typedef unsigned short u16;
typedef unsigned int   u32;
typedef __attribute__((ext_vector_type(4))) float  f32x4;
typedef __attribute__((ext_vector_type(8))) __bf16 bf16x8;

#define PSW   1056    // fallback: staged padded-image row width
#define ASTR  72      // LDS row stride (elems) for Bs (and fallback As): 64 + 8 pad
#define CFW   4128    // Cfull row stride (elems); valid cols 0..4119

// ws layout (bytes)
#define WS_BT  0u
#define WS_CF  1048576u                       // Bt: 512*1024*2
#define WS_AB  (1048576u + 16908288u)         // Cfull: 64*32*4128*2
#define WS_NEED (1048576u + 16908288u + 4194304u)  // + Abound: 64*32*512*2*2

static __device__ __forceinline__ float b2f(u32 u) {
  union { u32 i; float f; } c; c.i = u << 16; return c.f;
}
static __device__ __forceinline__ u16 f2b(float f) {
  union { float f; u32 i; } c; c.f = f;
  return (u16)((c.i + 0x7FFFu + ((c.i >> 16) & 1u)) >> 16);  // RNE
}
// padded-image read: x in padded coords [0,4120); 1.0 side pads, caller handles h
static __device__ __forceinline__ float padrd(const float* row, int x) {
  return (x < 12 || x >= 4108) ? 1.0f : row[x - 12];
}

// ---- kernel 0: transpose+cast lin_w (fp32, K=1024 x N=512) -> Bt (bf16, N=512 x K=1024)
__global__ __launch_bounds__(256) void transpose_w(const float* __restrict__ lw,
                                                   u16* __restrict__ bt) {
  __shared__ u16 tile[64][65];
  const int t  = threadIdx.x;
  const int c  = t & 63, r0 = t >> 6;
  const int n0 = blockIdx.x * 64;   // N=512 -> grid.x = 8
  const int k0 = blockIdx.y * 64;   // K=1024 -> grid.y = 16
#pragma unroll
  for (int rr = 0; rr < 16; ++rr) {
    const int r = r0 * 16 + rr;
    tile[r][c] = f2b(lw[(size_t)(k0 + r) * 512 + n0 + c]);
  }
  __syncthreads();
#pragma unroll
  for (int rr = 0; rr < 16; ++rr) {
    const int r = r0 * 16 + rr;
    bt[(size_t)(n0 + r) * 1024 + k0 + c] = tile[c][r];
  }
}

// ---- kernel 1: full-image conv+bias+relu -> Cfull bf16 [64][32][CFW]
// Interior slice columns (j=1..30) equal this full conv at x=8s+j.
__global__ __launch_bounds__(256) void conv_full(const float* __restrict__ img,
                                                 const float* __restrict__ cw,
                                                 const float* __restrict__ cb,
                                                 u16* __restrict__ cf) {
  const int b = blockIdx.x, h = blockIdx.y;   // 64 x 32
  const float* imgb = img + (size_t)b * 32 * 4096;
  float w[9];
#pragma unroll
  for (int i = 0; i < 9; ++i) w[i] = cw[i];
  const float bias = cb[0];
  u16* dst = cf + (size_t)(b * 32 + h) * CFW;
  for (int x = threadIdx.x; x < 4120; x += 256) {
    float o = bias;
#pragma unroll
    for (int dr = 0; dr < 3; ++dr) {
      const int hh = h - 1 + dr;
      if (hh < 0 || hh > 31) continue;        // vertical zero pad
      const float* row = imgb + hh * 4096;
#pragma unroll
      for (int dc = 0; dc < 3; ++dc) {
        const int xx = x - 1 + dc;
        const float v = (xx < 0 || xx >= 4120) ? 0.0f : padrd(row, xx);
        o += w[dr * 3 + dc] * v;
      }
    }
    dst[x] = f2b(fmaxf(o, 0.f));
  }
}

// ---- kernel 2: per-slice boundary columns j=0 / j=31 -> Abound u32 [(b*32+h)*512+s]
__global__ __launch_bounds__(256) void boundary_k(const float* __restrict__ img,
                                                  const float* __restrict__ cw,
                                                  const float* __restrict__ cb,
                                                  u32* __restrict__ ab) {
  const int b = blockIdx.x, h = blockIdx.y;   // 64 x 32
  const float* imgb = img + (size_t)b * 32 * 4096;
  float w[9];
#pragma unroll
  for (int i = 0; i < 9; ++i) w[i] = cw[i];
  const float bias = cb[0];
  for (int s = threadIdx.x; s < 512; s += 256) {
    const int X0 = 8 * s;
    float o0 = bias, o1 = bias;
#pragma unroll
    for (int dr = 0; dr < 3; ++dr) {
      const int hh = h - 1 + dr;
      if (hh < 0 || hh > 31) continue;
      const float* row = imgb + hh * 4096;
      // j=0: left neighbor zeroed -> only w[.][1]*P[X0] + w[.][2]*P[X0+1]
      o0 += w[dr * 3 + 1] * padrd(row, X0)      + w[dr * 3 + 2] * padrd(row, X0 + 1);
      // j=31: right neighbor zeroed -> w[.][0]*P[X0+30] + w[.][1]*P[X0+31]
      o1 += w[dr * 3 + 0] * padrd(row, X0 + 30) + w[dr * 3 + 1] * padrd(row, X0 + 31);
    }
    const u32 pk = (u32)f2b(fmaxf(o0, 0.f)) | ((u32)f2b(fmaxf(o1, 0.f)) << 16);
    ab[(size_t)(b * 32 + h) * 512 + s] = pk;
  }
}

// ---- kernel 3: GEMM (M=32768,K=1024,N=512), A-frags read straight from Cfull rows
__global__ __launch_bounds__(256) void gemm_k(
    const u16* __restrict__ cf,    // Cfull bf16
    const u32* __restrict__ ab,    // Abound packed
    const u16* __restrict__ bt,    // lin_w^T bf16 (512x1024)
    const float* __restrict__ lb,  // lin_b fp32
    float* __restrict__ out)       // (64,512,512) fp32
{
  // smem: Ps 4224B | Ab32 1024B | Bs 18432B = 23680B; epilogue reuses as Cs (16896B)
  __shared__ __align__(16) char sm[23680];
  u16* Ps   = (u16*)sm;            // [2][1056]
  u32* Ab32 = (u32*)(sm + 4224);   // [2][128]
  u16* Bs   = (u16*)(sm + 5248);   // [128][ASTR]
  float* Cs = (float*)sm;          // epilogue [32][132]

  const int t  = threadIdx.x;
  const int nt = blockIdx.x;        // 0..3
  const int mt = blockIdx.y;        // 0..255
  const int b  = mt >> 2;
  const int s0 = (mt & 3) << 7;
  const int n0 = nt << 7;

  const int wv = t >> 6, l = t & 63;
  const int wr = wv >> 1, wc = wv & 1;     // 2x2 wave grid over 128x128
  const int lq = l >> 4,  lr = l & 15;

  f32x4 acc[4][4];
#pragma unroll
  for (int i = 0; i < 4; ++i)
#pragma unroll
    for (int j = 0; j < 4; ++j) acc[i][j] = (f32x4)0.0f;

  // Ps staging map: 264 uint4 (132 per h-row)
  const int pr0 = (t >= 132) ? 1 : 0;
  const int pc0 = t - pr0 * 132;               // t<256 always < 264
  const int pr1 = 1, pc1 = (256 + t) - 132;    // only t<8
  const int abr = t >> 7, abc = t & 127;       // Ab staging

  for (int kk = 0; kk < 16; ++kk) {
    const int h0 = kk << 1;

    // global -> regs (no LDS touch yet)
    uint4 bsv[4];
#pragma unroll
    for (int p = 0; p < 4; ++p) {
      const int idx8 = t + (p << 8);
      const int n = idx8 >> 3, k8 = idx8 & 7;
      bsv[p] = *(const uint4*)(bt + (size_t)(n0 + n) * 1024 + (kk << 6) + (k8 << 3));
    }
    uint4 pv0 = *(const uint4*)(cf + (size_t)(b * 32 + h0 + pr0) * CFW + (s0 << 3) + (pc0 << 3));
    uint4 pv1;
    if (t < 8)
      pv1 = *(const uint4*)(cf + (size_t)(b * 32 + h0 + pr1) * CFW + (s0 << 3) + (pc1 << 3));
    const u32 abv = ab[(size_t)(b * 32 + h0 + abr) * 512 + s0 + abc];

    __syncthreads();   // prev iteration's frag reads done

    *(uint4*)(Ps + (pr0 * 1056) + (pc0 << 3)) = pv0;
    if (t < 8) *(uint4*)(Ps + 1056 + (pc1 << 3)) = pv1;
    Ab32[t] = abv;
#pragma unroll
    for (int p = 0; p < 4; ++p) {
      const int idx8 = t + (p << 8);
      const int n = idx8 >> 3, k8 = idx8 & 7;
      *(uint4*)(Bs + n * ASTR + (k8 << 3)) = bsv[p];
    }
    __syncthreads();

#pragma unroll
    for (int kc = 0; kc < 2; ++kc) {
      bf16x8 af[4], bfv[4];
#pragma unroll
      for (int im = 0; im < 4; ++im) {
        const int ml = wr * 64 + im * 16 + lr;
        af[im] = __builtin_bit_cast(bf16x8,
            *(const uint4*)(Ps + kc * 1056 + (ml << 3) + (lq << 3)));
        // boundary fixup: j==0 at lq==0 elem0; j==31 at lq==3 elem7
        const u32 a32 = Ab32[kc * 128 + ml];
        union { u16 u; __bf16 h; } lo, hi;
        lo.u = (u16)(a32 & 0xffffu); hi.u = (u16)(a32 >> 16);
        if (lq == 0) af[im][0] = lo.h;
        if (lq == 3) af[im][7] = hi.h;
      }
#pragma unroll
      for (int jn = 0; jn < 4; ++jn)
        bfv[jn] = __builtin_bit_cast(bf16x8,
            *(const uint4*)(Bs + (wc * 64 + jn * 16 + lr) * ASTR + (kc << 5) + (lq << 3)));
#pragma unroll
      for (int im = 0; im < 4; ++im)
#pragma unroll
        for (int jn = 0; jn < 4; ++jn)
          acc[im][jn] = __builtin_amdgcn_mfma_f32_16x16x32_bf16(
              af[im], bfv[jn], acc[im][jn], 0, 0, 0);
    }
  }

  // epilogue: +lin_b, LDS transpose, coalesced float4 row stores
  float lbv[4];
#pragma unroll
  for (int jn = 0; jn < 4; ++jn) lbv[jn] = lb[n0 + wc * 64 + jn * 16 + lr];

  const int erow = t >> 3, ecol = (t & 7) << 4;   // 32 rows x 8 col-chunks of 16
  const int grow_base = (mt << 7) + ((erow >> 4) * 64) + (erow & 15);

#pragma unroll
  for (int im = 0; im < 4; ++im) {
    __syncthreads();   // Cs free (prev chunk stores / last MFMA frag reads done)
#pragma unroll
    for (int jn = 0; jn < 4; ++jn) {
      const int cl = wc * 64 + jn * 16 + lr;
#pragma unroll
      for (int r = 0; r < 4; ++r)
        Cs[(wr * 16 + lq * 4 + r) * 132 + cl] = acc[im][jn][r] + lbv[jn];
    }
    __syncthreads();
    const size_t grow = (size_t)(grow_base + im * 16);
    float* orow = out + grow * 512 + n0 + ecol;
    const float* crow = Cs + erow * 132 + ecol;
#pragma unroll
    for (int p = 0; p < 4; ++p)
      *(f32x4*)(orow + p * 4) = *(const f32x4*)(crow + p * 4);
  }
}

// ================= fallback (round-2 fused path, needs only 1MB ws) =================
__global__ __launch_bounds__(256) void fused_fallback(
    const float* __restrict__ img, const float* __restrict__ cw,
    const float* __restrict__ cb, const u16* __restrict__ bt,
    const float* __restrict__ lb, float* __restrict__ out)
{
  __shared__ __align__(16) u16 Ps[4 * PSW];
  __shared__ __align__(16) u16 As[128 * ASTR];
  __shared__ __align__(16) u16 Bs[128 * ASTR];
  const int t = threadIdx.x, nt = blockIdx.x, mt = blockIdx.y;
  const int b = mt >> 2, s0 = (mt & 3) << 7, X0 = s0 << 3, n0 = nt << 7;
  const float* imgb = img + (size_t)b * 32 * 4096;
  float cwf[9];
#pragma unroll
  for (int i = 0; i < 9; ++i) cwf[i] = cw[i];
  const float bias = cb[0];
  const int wv = t >> 6, l = t & 63;
  const int wr = wv >> 1, wc = wv & 1, lq = l >> 4, lr = l & 15;
  const int sl = t >> 1, hsel = t & 1;
  f32x4 acc[4][4];
#pragma unroll
  for (int i = 0; i < 4; ++i)
#pragma unroll
    for (int j = 0; j < 4; ++j) acc[i][j] = (f32x4)0.0f;
  for (int kk = 0; kk < 16; ++kk) {
    const int h0 = kk << 1;
    __syncthreads();
    uint4 bsv[4];
#pragma unroll
    for (int p = 0; p < 4; ++p) {
      const int idx8 = t + (p << 8);
      const int n = idx8 >> 3, k8 = idx8 & 7;
      bsv[p] = *(const uint4*)(bt + (size_t)(n0 + n) * 1024 + (kk << 6) + (k8 << 3));
    }
    for (int idx = t; idx < 4 * PSW; idx += 256) {
      const int r = idx / PSW, xi = idx - r * PSW;
      const int h = h0 - 1 + r, x = X0 - 1 + xi;
      u16 v = 0;
      if (h >= 0 && h < 32 && x >= 0 && x < 4120)
        v = (x < 12 || x >= 4108) ? (u16)0x3F80 : f2b(imgb[h * 4096 + (x - 12)]);
      Ps[idx] = v;
    }
    __syncthreads();
    {
      const int pbase = (sl << 3);
#pragma unroll
      for (int wb = 0; wb < 32; wb += 16) {
        float o[16];
#pragma unroll
        for (int j = 0; j < 16; ++j) o[j] = bias;
#pragma unroll
        for (int dr = 0; dr < 3; ++dr) {
          const u16* p = Ps + (hsel + dr) * PSW + pbase + wb;
          const uint4 va = *(const uint4*)p;
          const uint4 vb = *(const uint4*)(p + 8);
          const u32   vc = *(const u32*)(p + 16);
          float win[18];
          win[0] = b2f(va.x & 0xffffu); win[1] = b2f(va.x >> 16);
          win[2] = b2f(va.y & 0xffffu); win[3] = b2f(va.y >> 16);
          win[4] = b2f(va.z & 0xffffu); win[5] = b2f(va.z >> 16);
          win[6] = b2f(va.w & 0xffffu); win[7] = b2f(va.w >> 16);
          win[8] = b2f(vb.x & 0xffffu); win[9] = b2f(vb.x >> 16);
          win[10] = b2f(vb.y & 0xffffu); win[11] = b2f(vb.y >> 16);
          win[12] = b2f(vb.z & 0xffffu); win[13] = b2f(vb.z >> 16);
          win[14] = b2f(vb.w & 0xffffu); win[15] = b2f(vb.w >> 16);
          win[16] = b2f(vc & 0xffffu);   win[17] = b2f(vc >> 16);
          if (wb == 0) win[0] = 0.f; else win[17] = 0.f;
          const float w0 = cwf[dr * 3], w1 = cwf[dr * 3 + 1], w2 = cwf[dr * 3 + 2];
#pragma unroll
          for (int j = 0; j < 16; ++j)
            o[j] += w0 * win[j] + w1 * win[j + 1] + w2 * win[j + 2];
        }
        u32 pk[8];
#pragma unroll
        for (int q = 0; q < 8; ++q)
          pk[q] = (u32)f2b(fmaxf(o[2 * q], 0.f)) | ((u32)f2b(fmaxf(o[2 * q + 1], 0.f)) << 16);
        uint4* dst = (uint4*)(As + sl * ASTR + (hsel << 5) + wb);
        dst[0] = make_uint4(pk[0], pk[1], pk[2], pk[3]);
        dst[1] = make_uint4(pk[4], pk[5], pk[6], pk[7]);
      }
    }
#pragma unroll
    for (int p = 0; p < 4; ++p) {
      const int idx8 = t + (p << 8);
      const int n = idx8 >> 3, k8 = idx8 & 7;
      *(uint4*)(Bs + n * ASTR + (k8 << 3)) = bsv[p];
    }
    __syncthreads();
#pragma unroll
    for (int kc = 0; kc < 2; ++kc) {
      const int ko = (kc << 5) + (lq << 3);
      bf16x8 af[4], bfv[4];
#pragma unroll
      for (int im = 0; im < 4; ++im)
        af[im] = __builtin_bit_cast(bf16x8,
            *(const uint4*)(As + (wr * 64 + im * 16 + lr) * ASTR + ko));
#pragma unroll
      for (int jn = 0; jn < 4; ++jn)
        bfv[jn] = __builtin_bit_cast(bf16x8,
            *(const uint4*)(Bs + (wc * 64 + jn * 16 + lr) * ASTR + ko));
#pragma unroll
      for (int im = 0; im < 4; ++im)
#pragma unroll
        for (int jn = 0; jn < 4; ++jn)
          acc[im][jn] = __builtin_amdgcn_mfma_f32_16x16x32_bf16(
              af[im], bfv[jn], acc[im][jn], 0, 0, 0);
    }
  }
#pragma unroll
  for (int jn = 0; jn < 4; ++jn) {
    const int col = n0 + wc * 64 + jn * 16 + lr;
    const float lbv = lb[col];
#pragma unroll
    for (int im = 0; im < 4; ++im) {
      const int row0 = (mt << 7) + wr * 64 + im * 16 + (lq << 2);
#pragma unroll
      for (int r = 0; r < 4; ++r)
        out[(size_t)(row0 + r) * 512 + col] = acc[im][jn][r] + lbv;
    }
  }
}

extern "C" void kernel_launch(void* const* d_in, const int* in_sizes, int n_in,
                              void* d_out, int out_size, void* d_ws, size_t ws_size,
                              hipStream_t stream) {
  const float* img = (const float*)d_in[0];
  const float* cw  = (const float*)d_in[1];
  const float* cb  = (const float*)d_in[2];
  const float* lw  = (const float*)d_in[3];
  const float* lb  = (const float*)d_in[4];
  float* out = (float*)d_out;

  u16* btw = (u16*)((char*)d_ws + WS_BT);
  transpose_w<<<dim3(8, 16), 256, 0, stream>>>(lw, btw);

  if (ws_size >= WS_NEED) {
    u16* cf = (u16*)((char*)d_ws + WS_CF);
    u32* ab = (u32*)((char*)d_ws + WS_AB);
    conv_full<<<dim3(64, 32), 256, 0, stream>>>(img, cw, cb, cf);
    boundary_k<<<dim3(64, 32), 256, 0, stream>>>(img, cw, cb, ab);
    gemm_k<<<dim3(4, 256), 256, 0, stream>>>(cf, ab, btw, lb, out);
  } else {
    fused_fallback<<<dim3(4, 256), 256, 0, stream>>>(img, cw, cb, btw, lb, out);
  }
}

// Round 4
// 170.370 us; speedup vs baseline: 2.3255x; 1.4451x over previous
//
#include <hip/hip_runtime.h>
#include <cstdint>
#include <cstddef>

typedef unsigned short u16;
typedef unsigned int   u32;
typedef __attribute__((ext_vector_type(4))) float  f32x4;
typedef __attribute__((ext_vector_type(8))) __bf16 bf16x8;

#define PSW   1056    // fallback: staged padded-image row width
#define ASTR  72      // fallback LDS row stride
#define CFW   4128    // Cfull row stride (elems); data cols 0..4119, zeros to 4127
#define RPAD  4144    // prep: padded row floats (4120 data + 24 zero slack)

// ws layout (bytes)
#define WS_BT  0u
#define WS_CF  1048576u                       // Bt: 512*1024*2
#define WS_AB  (1048576u + 16908288u)         // Cfull: 64*32*4128*2
#define WS_NEED (1048576u + 16908288u + 4194304u)  // + Abound: 64*32*512*4

static __device__ __forceinline__ float b2f(u32 u) {
  union { u32 i; float f; } c; c.i = u << 16; return c.f;
}
static __device__ __forceinline__ u16 f2b(float f) {
  union { float f; u32 i; } c; c.f = f;
  return (u16)((c.i + 0x7FFFu + ((c.i >> 16) & 1u)) >> 16);  // RNE
}

// async global->LDS DMA. LDS dest is WAVE-UNIFORM base + lane*size (m104).
static __device__ __forceinline__ void gl_lds16(const void* g, void* l) {
  __builtin_amdgcn_global_load_lds(
      (__attribute__((address_space(1))) unsigned int*)(void*)g,
      (__attribute__((address_space(3))) unsigned int*)l, 16, 0, 0);
}
static __device__ __forceinline__ void gl_lds4(const void* g, void* l) {
  __builtin_amdgcn_global_load_lds(
      (__attribute__((address_space(1))) unsigned int*)(void*)g,
      (__attribute__((address_space(3))) unsigned int*)l, 4, 0, 0);
}

// ---- kernel 0: transpose+cast lin_w (fp32, K=1024 x N=512) -> Bt (bf16, N=512 x K=1024)
__global__ __launch_bounds__(256) void transpose_w(const float* __restrict__ lw,
                                                   u16* __restrict__ bt) {
  __shared__ u16 tile[64][65];
  const int t  = threadIdx.x;
  const int c  = t & 63, r0 = t >> 6;
  const int n0 = blockIdx.x * 64;
  const int k0 = blockIdx.y * 64;
#pragma unroll
  for (int rr = 0; rr < 16; ++rr) {
    const int r = r0 * 16 + rr;
    tile[r][c] = f2b(lw[(size_t)(k0 + r) * 512 + n0 + c]);
  }
  __syncthreads();
#pragma unroll
  for (int rr = 0; rr < 16; ++rr) {
    const int r = r0 * 16 + rr;
    bt[(size_t)(n0 + r) * 1024 + k0 + c] = tile[c][r];
  }
}

// ---- kernel 1: fused full-image conv+bias+relu -> Cfull bf16, and slice-boundary
// columns j=0/31 -> Abound. 3 fp32 rows staged in LDS once, vectorized compute.
__global__ __launch_bounds__(256) void prep(
    const float* __restrict__ img, const float* __restrict__ cw,
    const float* __restrict__ cb, u16* __restrict__ cf, u32* __restrict__ ab)
{
  __shared__ __align__(16) float R[3][RPAD];   // 49.7 KB
  const int b = blockIdx.x, h = blockIdx.y, t = threadIdx.x;
  const float* imgb = img + (size_t)b * 32 * 4096;
#pragma unroll
  for (int r = 0; r < 3; ++r) {
    const int hh = h - 1 + r;
    const int live = (hh >= 0 && hh <= 31);
    const float* row = imgb + (ptrdiff_t)hh * 4096;
    for (int k = t; k < 1024; k += 256) {
      f32x4 v = (f32x4)0.0f;
      if (live) v = *(const f32x4*)(row + (k << 2));
      *(f32x4*)(&R[r][12 + (k << 2)]) = v;   // padded coords 12..4107
    }
    if (t < 12)      R[r][t] = live ? 1.0f : 0.0f;          // left 1.0 pad
    else if (t < 24) R[r][4096 + t] = live ? 1.0f : 0.0f;   // right 1.0 pad 4108..4119
    else if (t < 48) R[r][4096 + t] = 0.0f;                 // zero slack 4120..4143
  }
  __syncthreads();
  float w[9];
#pragma unroll
  for (int q = 0; q < 9; ++q) w[q] = cw[q];
  const float bias = cb[0];
  u16* dst = cf + (size_t)(b * 32 + h) * CFW;
  for (int c = t; c < 258; c += 256) {       // chunk c: out x in [16c,16c+16)
    float wf[3][24];                          // window coords [16c-4, 16c+20)
#pragma unroll
    for (int r = 0; r < 3; ++r) {
      const f32x4* Rr = (const f32x4*)&R[r][0];
      f32x4 m = (f32x4)0.0f;
      if (c != 0) m = Rr[4 * c - 1];
      *(f32x4*)&wf[r][0] = m;
#pragma unroll
      for (int u = 1; u < 6; ++u) *(f32x4*)&wf[r][4 * u] = Rr[4 * c - 1 + u];
    }
    float o[16];
#pragma unroll
    for (int j = 0; j < 16; ++j) o[j] = bias;
#pragma unroll
    for (int r = 0; r < 3; ++r) {
      const float w0 = w[r * 3], w1 = w[r * 3 + 1], w2 = w[r * 3 + 2];
#pragma unroll
      for (int j = 0; j < 16; ++j)
        o[j] += w0 * wf[r][j + 3] + w1 * wf[r][j + 4] + w2 * wf[r][j + 5];
    }
    const int xbase = c << 4;
    u32 pk[8];
#pragma unroll
    for (int q = 0; q < 8; ++q) {
      const int x0 = xbase + 2 * q;
      const u32 lo = (x0     < 4120) ? (u32)f2b(fmaxf(o[2 * q],     0.f)) : 0u;
      const u32 hi = (x0 + 1 < 4120) ? (u32)f2b(fmaxf(o[2 * q + 1], 0.f)) : 0u;
      pk[q] = lo | (hi << 16);
    }
    uint4* dp = (uint4*)(dst + xbase);
    dp[0] = make_uint4(pk[0], pk[1], pk[2], pk[3]);
    dp[1] = make_uint4(pk[4], pk[5], pk[6], pk[7]);
  }
  // boundary cols j=0 / j=31 per slice (zero rows in LDS make vertical pad free)
  u32* abrow = ab + (size_t)(b * 32 + h) * 512;
#pragma unroll
  for (int ss = 0; ss < 2; ++ss) {
    const int s = t + ss * 256;
    const int X0 = s << 3;
    float o0 = bias, o1 = bias;
#pragma unroll
    for (int r = 0; r < 3; ++r) {
      o0 += w[r * 3 + 1] * R[r][X0]      + w[r * 3 + 2] * R[r][X0 + 1];
      o1 += w[r * 3 + 0] * R[r][X0 + 30] + w[r * 3 + 1] * R[r][X0 + 31];
    }
    abrow[s] = (u32)f2b(fmaxf(o0, 0.f)) | ((u32)f2b(fmaxf(o1, 0.f)) << 16);
  }
}

// ---- kernel 2: GEMM (M=32768,K=1024,N=512) with global_load_lds staging
__global__ __launch_bounds__(256) void gemm_k(
    const u16* __restrict__ cf, const u32* __restrict__ ab,
    const u16* __restrict__ bt, const float* __restrict__ lb,
    float* __restrict__ out)
{
  // Ps [2][1056] u16 (4224B) | Ab32 [256] u32 (1024B) | Bs 128x64 swizzled u16 (16384B)
  __shared__ __align__(16) char sm[4224 + 1024 + 16384];
  u16* Ps   = (u16*)sm;
  u32* Ab32 = (u32*)(sm + 4224);
  u16* Bs   = (u16*)(sm + 5248);
  float* Cs = (float*)sm;          // epilogue reuse [32][132]

  const int t  = threadIdx.x;
  const int nt = blockIdx.x, mt = blockIdx.y;
  const int b  = mt >> 2, s0 = (mt & 3) << 7, n0 = nt << 7;
  const int w  = t >> 6, i = t & 63;
  const int wr = w >> 1, wc = w & 1;
  const int lq = i >> 4, lr = i & 15;

  // B staging: chunk q = w*256 + j*64 + i -> n = w*32 + j*8 + (i>>3), c = (i&7)^((i>>3)&7)
  // LDS chunk index = n*8 + (c ^ (n&7))  (XOR swizzle; DMA order == storage order)
  const int cB = (i & 7) ^ ((i >> 3) & 7);
  const u16* btp = bt + (size_t)(n0 + (w << 5) + (i >> 3)) * 1024 + (cB << 3);
  u16* BsW = Bs + (w << 11);                    // wave-uniform, + j*512 elems per call

  // Ps staging: chunk q = t (264 chunks; tail 256..263 by t<8)
  const int rP  = (t >= 132) ? 1 : 0;
  const int ccP = t - 132 * rP;
  const u16* cfp  = cf + (size_t)(b * 32 + rP) * CFW + (s0 << 3) + (ccP << 3);
  const u16* cfp2 = cf + (size_t)(b * 32 + 1) * CFW + (s0 << 3) + ((124 + t) << 3);
  u16* PsW = Ps + (w << 9);                     // wave-uniform

  // Ab staging: dword d = t
  const u32* abp = ab + (size_t)(b * 32 + (t >> 7)) * 512 + s0 + (t & 127);
  u32* AbW = Ab32 + (w << 6);                   // wave-uniform

  f32x4 acc[4][4];
#pragma unroll
  for (int a = 0; a < 4; ++a)
#pragma unroll
    for (int c = 0; c < 4; ++c) acc[a][c] = (f32x4)0.0f;

  for (int kk = 0; kk < 16; ++kk) {
    __syncthreads();                 // all waves done reading prev tiles
    gl_lds16(btp,              BsW);
    gl_lds16(btp +  8 * 1024,  BsW + 512);
    gl_lds16(btp + 16 * 1024,  BsW + 1024);
    gl_lds16(btp + 24 * 1024,  BsW + 1536);
    gl_lds16(cfp, PsW);
    if (t < 8) gl_lds16(cfp2, Ps + 2048);
    gl_lds4(abp, AbW);
    btp += 64; cfp += 2 * CFW; cfp2 += 2 * CFW; abp += 1024;
    __syncthreads();                 // drains vmcnt(0): DMA complete

#pragma unroll
    for (int kc = 0; kc < 2; ++kc) {
      const int bswz = (((kc << 2) + lq) ^ (lr & 7)) << 3;
      bf16x8 af[4], bfv[4];
#pragma unroll
      for (int im = 0; im < 4; ++im) {
        const int ml = wr * 64 + im * 16 + lr;
        af[im] = __builtin_bit_cast(bf16x8,
            *(const uint4*)(Ps + kc * 1056 + ((ml + lq) << 3)));
        const u32 a32 = Ab32[kc * 128 + ml];   // same addr for 4 lq -> broadcast
        union { u16 u; __bf16 h; } lo, hi;
        lo.u = (u16)(a32 & 0xffffu); hi.u = (u16)(a32 >> 16);
        if (lq == 0) af[im][0] = lo.h;         // slice col j=0
        if (lq == 3) af[im][7] = hi.h;         // slice col j=31
      }
#pragma unroll
      for (int jn = 0; jn < 4; ++jn) {
        const int n = wc * 64 + jn * 16 + lr;
        bfv[jn] = __builtin_bit_cast(bf16x8, *(const uint4*)(Bs + (n << 6) + bswz));
      }
#pragma unroll
      for (int im = 0; im < 4; ++im)
#pragma unroll
        for (int jn = 0; jn < 4; ++jn)
          acc[im][jn] = __builtin_amdgcn_mfma_f32_16x16x32_bf16(
              af[im], bfv[jn], acc[im][jn], 0, 0, 0);
    }
  }

  // epilogue: +lin_b, LDS transpose, coalesced float4 row stores
  float lbv[4];
#pragma unroll
  for (int jn = 0; jn < 4; ++jn) lbv[jn] = lb[n0 + wc * 64 + jn * 16 + lr];

  const int erow = t >> 3, ecol = (t & 7) << 4;
  const int grow_base = (mt << 7) + ((erow >> 4) * 64) + (erow & 15);

#pragma unroll
  for (int im = 0; im < 4; ++im) {
    __syncthreads();
#pragma unroll
    for (int jn = 0; jn < 4; ++jn) {
      const int cl = wc * 64 + jn * 16 + lr;
#pragma unroll
      for (int r = 0; r < 4; ++r)
        Cs[(wr * 16 + lq * 4 + r) * 132 + cl] = acc[im][jn][r] + lbv[jn];
    }
    __syncthreads();
    const size_t grow = (size_t)(grow_base + im * 16);
    float* orow = out + grow * 512 + n0 + ecol;
    const float* crow = Cs + erow * 132 + ecol;
#pragma unroll
    for (int p = 0; p < 4; ++p)
      *(f32x4*)(orow + p * 4) = *(const f32x4*)(crow + p * 4);
  }
}

// ================= fallback (round-2 fused path, needs only 1MB ws) =================
__global__ __launch_bounds__(256) void fused_fallback(
    const float* __restrict__ img, const float* __restrict__ cw,
    const float* __restrict__ cb, const u16* __restrict__ bt,
    const float* __restrict__ lb, float* __restrict__ out)
{
  __shared__ __align__(16) u16 Ps[4 * PSW];
  __shared__ __align__(16) u16 As[128 * ASTR];
  __shared__ __align__(16) u16 Bs[128 * ASTR];
  const int t = threadIdx.x, nt = blockIdx.x, mt = blockIdx.y;
  const int b = mt >> 2, s0 = (mt & 3) << 7, X0 = s0 << 3, n0 = nt << 7;
  const float* imgb = img + (size_t)b * 32 * 4096;
  float cwf[9];
#pragma unroll
  for (int q = 0; q < 9; ++q) cwf[q] = cw[q];
  const float bias = cb[0];
  const int wv = t >> 6, l = t & 63;
  const int wr = wv >> 1, wc = wv & 1, lq = l >> 4, lr = l & 15;
  const int sl = t >> 1, hsel = t & 1;
  f32x4 acc[4][4];
#pragma unroll
  for (int a = 0; a < 4; ++a)
#pragma unroll
    for (int c = 0; c < 4; ++c) acc[a][c] = (f32x4)0.0f;
  for (int kk = 0; kk < 16; ++kk) {
    const int h0 = kk << 1;
    __syncthreads();
    uint4 bsv[4];
#pragma unroll
    for (int p = 0; p < 4; ++p) {
      const int idx8 = t + (p << 8);
      const int n = idx8 >> 3, k8 = idx8 & 7;
      bsv[p] = *(const uint4*)(bt + (size_t)(n0 + n) * 1024 + (kk << 6) + (k8 << 3));
    }
    for (int idx = t; idx < 4 * PSW; idx += 256) {
      const int r = idx / PSW, xi = idx - r * PSW;
      const int h = h0 - 1 + r, x = X0 - 1 + xi;
      u16 v = 0;
      if (h >= 0 && h < 32 && x >= 0 && x < 4120)
        v = (x < 12 || x >= 4108) ? (u16)0x3F80 : f2b(imgb[h * 4096 + (x - 12)]);
      Ps[idx] = v;
    }
    __syncthreads();
    {
      const int pbase = (sl << 3);
#pragma unroll
      for (int wb = 0; wb < 32; wb += 16) {
        float o[16];
#pragma unroll
        for (int j = 0; j < 16; ++j) o[j] = bias;
#pragma unroll
        for (int dr = 0; dr < 3; ++dr) {
          const u16* p = Ps + (hsel + dr) * PSW + pbase + wb;
          const uint4 va = *(const uint4*)p;
          const uint4 vb = *(const uint4*)(p + 8);
          const u32   vc = *(const u32*)(p + 16);
          float win[18];
          win[0] = b2f(va.x & 0xffffu); win[1] = b2f(va.x >> 16);
          win[2] = b2f(va.y & 0xffffu); win[3] = b2f(va.y >> 16);
          win[4] = b2f(va.z & 0xffffu); win[5] = b2f(va.z >> 16);
          win[6] = b2f(va.w & 0xffffu); win[7] = b2f(va.w >> 16);
          win[8] = b2f(vb.x & 0xffffu); win[9] = b2f(vb.x >> 16);
          win[10] = b2f(vb.y & 0xffffu); win[11] = b2f(vb.y >> 16);
          win[12] = b2f(vb.z & 0xffffu); win[13] = b2f(vb.z >> 16);
          win[14] = b2f(vb.w & 0xffffu); win[15] = b2f(vb.w >> 16);
          win[16] = b2f(vc & 0xffffu);   win[17] = b2f(vc >> 16);
          if (wb == 0) win[0] = 0.f; else win[17] = 0.f;
          const float w0 = cwf[dr * 3], w1 = cwf[dr * 3 + 1], w2 = cwf[dr * 3 + 2];
#pragma unroll
          for (int j = 0; j < 16; ++j)
            o[j] += w0 * win[j] + w1 * win[j + 1] + w2 * win[j + 2];
        }
        u32 pk[8];
#pragma unroll
        for (int q = 0; q < 8; ++q)
          pk[q] = (u32)f2b(fmaxf(o[2 * q], 0.f)) | ((u32)f2b(fmaxf(o[2 * q + 1], 0.f)) << 16);
        uint4* dst = (uint4*)(As + sl * ASTR + (hsel << 5) + wb);
        dst[0] = make_uint4(pk[0], pk[1], pk[2], pk[3]);
        dst[1] = make_uint4(pk[4], pk[5], pk[6], pk[7]);
      }
    }
#pragma unroll
    for (int p = 0; p < 4; ++p) {
      const int idx8 = t + (p << 8);
      const int n = idx8 >> 3, k8 = idx8 & 7;
      *(uint4*)(Bs + n * ASTR + (k8 << 3)) = bsv[p];
    }
    __syncthreads();
#pragma unroll
    for (int kc = 0; kc < 2; ++kc) {
      const int ko = (kc << 5) + (lq << 3);
      bf16x8 af[4], bfv[4];
#pragma unroll
      for (int im = 0; im < 4; ++im)
        af[im] = __builtin_bit_cast(bf16x8,
            *(const uint4*)(As + (wr * 64 + im * 16 + lr) * ASTR + ko));
#pragma unroll
      for (int jn = 0; jn < 4; ++jn)
        bfv[jn] = __builtin_bit_cast(bf16x8,
            *(const uint4*)(Bs + (wc * 64 + jn * 16 + lr) * ASTR + ko));
#pragma unroll
      for (int im = 0; im < 4; ++im)
#pragma unroll
        for (int jn = 0; jn < 4; ++jn)
          acc[im][jn] = __builtin_amdgcn_mfma_f32_16x16x32_bf16(
              af[im], bfv[jn], acc[im][jn], 0, 0, 0);
    }
  }
#pragma unroll
  for (int jn = 0; jn < 4; ++jn) {
    const int col = n0 + wc * 64 + jn * 16 + lr;
    const float lbv = lb[col];
#pragma unroll
    for (int im = 0; im < 4; ++im) {
      const int row0 = (mt << 7) + wr * 64 + im * 16 + (lq << 2);
#pragma unroll
      for (int r = 0; r < 4; ++r)
        out[(size_t)(row0 + r) * 512 + col] = acc[im][jn][r] + lbv;
    }
  }
}

extern "C" void kernel_launch(void* const* d_in, const int* in_sizes, int n_in,
                              void* d_out, int out_size, void* d_ws, size_t ws_size,
                              hipStream_t stream) {
  const float* img = (const float*)d_in[0];
  const float* cw  = (const float*)d_in[1];
  const float* cb  = (const float*)d_in[2];
  const float* lw  = (const float*)d_in[3];
  const float* lb  = (const float*)d_in[4];
  float* out = (float*)d_out;

  u16* btw = (u16*)((char*)d_ws + WS_BT);
  transpose_w<<<dim3(8, 16), 256, 0, stream>>>(lw, btw);

  if (ws_size >= WS_NEED) {
    u16* cf = (u16*)((char*)d_ws + WS_CF);
    u32* ab = (u32*)((char*)d_ws + WS_AB);
    prep<<<dim3(64, 32), 256, 0, stream>>>(img, cw, cb, cf, ab);
    gemm_k<<<dim3(4, 256), 256, 0, stream>>>(cf, ab, btw, lb, out);
  } else {
    fused_fallback<<<dim3(4, 256), 256, 0, stream>>>(img, cw, cb, btw, lb, out);
  }
}